// Round 1
// baseline (2521.959 us; speedup 1.0000x reference)
//
#include <hip/hip_runtime.h>

// GIN: 2x GINConv(eps=0, MLP 2-layer) + ReLU, then Linear(128->1).
// N=50000 nodes, E=800000 edges, IN=64, HID=128.
//
// Pipeline (all fp32):
//   agg1 = segment_sum(gather(x, src), dst)            [scatter atomics]
//   t1   = relu((x+agg1) @ W1 + b1)                    [gemm K=64]
//   h1   = relu(t1 @ W2 + b2)                          [gemm K=128]
//   agg2 = segment_sum(gather(h1, src), dst)
//   t2   = relu((h1+agg2) @ W3 + b3)
//   h2   = relu(t2 @ W4 + b4)
//   out  = h2 @ Wout + bout                            [dot per node]

#define N_NODES 50000
#define IN_CH 64
#define HID 128

// ---------------- edge dtype detection (int64 vs int32) ----------------
// jax.random.randint(dtype=int64) silently becomes int32 when x64 is off.
// If data is int64 (values < 2^31, non-negative), every odd int32 word is 0.
__global__ void detect64_kernel(const int* __restrict__ ei32, int* __restrict__ flag) {
    int t = threadIdx.x;  // 256 threads
    int v = ei32[2 * t + 1];
    unsigned long long b = __ballot(v != 0);
    __shared__ unsigned long long r[4];
    if ((t & 63) == 0) r[t >> 6] = b;
    __syncthreads();
    if (t == 0) flag[0] = ((r[0] | r[1] | r[2] | r[3]) == 0ULL) ? 1 : 0;
}

// ---------------- scatter-add (gather + atomic segment sum) ----------------
template<int C>
__global__ __launch_bounds__(256) void scatter_add_kernel(
    const float* __restrict__ h, const void* __restrict__ ei,
    const int* __restrict__ is64, float* __restrict__ agg, int E)
{
    constexpr int PER = C / 4;                 // float4 groups per row
    int tid = blockIdx.x * blockDim.x + threadIdx.x;
    int e = tid / PER;
    int g = tid % PER;
    if (e >= E) return;
    int s, d;
    if (*is64) {
        const long long* p = (const long long*)ei;
        s = (int)p[e]; d = (int)p[E + e];
    } else {
        const int* p = (const int*)ei;
        s = p[e]; d = p[E + e];
    }
    float4 v = *(const float4*)(h + (size_t)s * C + g * 4);
    float* q = agg + (size_t)d * C + g * 4;
    atomicAdd(q + 0, v.x);
    atomicAdd(q + 1, v.y);
    atomicAdd(q + 2, v.z);
    atomicAdd(q + 3, v.w);
}

// ---------------- fp32 GEMM: out[N][128] = act((A (+Aadd)) @ W + b) ----------------
// K = 64 or 128. 64 rows/block, 256 threads, 8x4 register tile per thread.
// LDS: Ws 64x128 (32KB) + As 64x68 (17.4KB) -> ~3 blocks/CU.
template<int K, bool RELU>
__global__ __launch_bounds__(256) void gemm_mlp_kernel(
    const float* __restrict__ A, const float* __restrict__ Aadd,
    const float* __restrict__ W, const float* __restrict__ bias,
    float* __restrict__ out, int N)
{
    constexpr int KT = 64;                 // K tile
    constexpr int NT = 64;                 // rows per block
    __shared__ float Ws[KT][128];
    __shared__ float As[NT][KT + 4];       // +4 keeps 16B alignment, breaks stride

    const int t  = threadIdx.x;
    const int tx = t & 31;                 // col group: cols tx*4 .. tx*4+3
    const int ty = t >> 5;                 // row group: rows ty*8 .. ty*8+7
    const int n0 = blockIdx.x * NT;

    float acc[8][4];
    #pragma unroll
    for (int i = 0; i < 8; i++)
        #pragma unroll
        for (int j = 0; j < 4; j++) acc[i][j] = 0.f;

    for (int k0 = 0; k0 < K; k0 += KT) {
        // stage W tile: KT x 128
        {
            int lr = t & 31;               // float4 index in row
            int kr = t >> 5;               // row, step 8
            #pragma unroll
            for (int r = 0; r < KT; r += 8) {
                float4 v = *(const float4*)(W + (size_t)(k0 + kr + r) * 128 + lr * 4);
                *(float4*)&Ws[kr + r][lr * 4] = v;
            }
        }
        // stage A tile: NT x KT  (optionally fused add of Aadd)
        {
            constexpr int F4 = KT / 4;     // 16 float4 per row
            int g = t % F4;
            int r = t / F4;                // 16 rows per pass
            #pragma unroll
            for (int rr = 0; rr < NT; rr += 256 / F4) {
                int row = r + rr;
                int n = n0 + row;
                int nc = n < N ? n : N - 1;   // clamp; stores guarded later
                float4 v = *(const float4*)(A + (size_t)nc * K + k0 + g * 4);
                if (Aadd) {
                    float4 u = *(const float4*)(Aadd + (size_t)nc * K + k0 + g * 4);
                    v.x += u.x; v.y += u.y; v.z += u.z; v.w += u.w;
                }
                *(float4*)&As[row][g * 4] = v;
            }
        }
        __syncthreads();
        #pragma unroll
        for (int k = 0; k < KT; k += 4) {
            float4 w0 = *(const float4*)&Ws[k + 0][tx * 4];
            float4 w1 = *(const float4*)&Ws[k + 1][tx * 4];
            float4 w2 = *(const float4*)&Ws[k + 2][tx * 4];
            float4 w3 = *(const float4*)&Ws[k + 3][tx * 4];
            #pragma unroll
            for (int i = 0; i < 8; i++) {
                float4 a = *(const float4*)&As[ty * 8 + i][k];
                acc[i][0] += a.x * w0.x + a.y * w1.x + a.z * w2.x + a.w * w3.x;
                acc[i][1] += a.x * w0.y + a.y * w1.y + a.z * w2.y + a.w * w3.y;
                acc[i][2] += a.x * w0.z + a.y * w1.z + a.z * w2.z + a.w * w3.z;
                acc[i][3] += a.x * w0.w + a.y * w1.w + a.z * w2.w + a.w * w3.w;
            }
        }
        __syncthreads();
    }
    // epilogue
    float4 b = *(const float4*)(bias + tx * 4);
    #pragma unroll
    for (int i = 0; i < 8; i++) {
        int n = n0 + ty * 8 + i;
        if (n < N) {
            float4 o;
            o.x = acc[i][0] + b.x; o.y = acc[i][1] + b.y;
            o.z = acc[i][2] + b.z; o.w = acc[i][3] + b.w;
            if (RELU) {
                o.x = fmaxf(o.x, 0.f); o.y = fmaxf(o.y, 0.f);
                o.z = fmaxf(o.z, 0.f); o.w = fmaxf(o.w, 0.f);
            }
            *(float4*)(out + (size_t)n * 128 + tx * 4) = o;
        }
    }
}

// ---------------- output head: out[n] = dot(h2[n], Wout) + bout ----------------
__global__ __launch_bounds__(256) void out_dot_kernel(
    const float* __restrict__ h2, const float* __restrict__ Wout,
    const float* __restrict__ bout, float* __restrict__ out, int N)
{
    int gt = blockIdx.x * blockDim.x + threadIdx.x;
    int wave = gt >> 6;
    int lane = threadIdx.x & 63;
    if (wave >= N) return;
    const float* row = h2 + (size_t)wave * 128;
    float p = row[lane] * Wout[lane] + row[lane + 64] * Wout[lane + 64];
    #pragma unroll
    for (int off = 32; off; off >>= 1) p += __shfl_down(p, off);
    if (lane == 0) out[wave] = p + bout[0];
}

extern "C" void kernel_launch(void* const* d_in, const int* in_sizes, int n_in,
                              void* d_out, int out_size, void* d_ws, size_t ws_size,
                              hipStream_t stream) {
    const float* x    = (const float*)d_in[0];
    const void*  ei   = d_in[1];
    const float* W1   = (const float*)d_in[2];
    const float* b1   = (const float*)d_in[3];
    const float* W2   = (const float*)d_in[4];
    const float* b2   = (const float*)d_in[5];
    const float* W3   = (const float*)d_in[6];
    const float* b3   = (const float*)d_in[7];
    const float* W4   = (const float*)d_in[8];
    const float* b4   = (const float*)d_in[9];
    const float* Wout = (const float*)d_in[10];
    const float* bout = (const float*)d_in[11];
    float* out = (float*)d_out;

    const int E = in_sizes[1] / 2;
    const int N = N_NODES;

    char* wsb = (char*)d_ws;
    int*   flag = (int*)wsb;                                  // 256B slot
    float* bufA = (float*)(wsb + 256);                        // N*128 (agg)
    float* bufB = bufA + (size_t)N * HID;                     // N*128
    float* bufC = bufB + (size_t)N * HID;                     // N*128
    // total ws: 256B + 3 * 25.6MB = ~76.8MB

    detect64_kernel<<<1, 256, 0, stream>>>((const int*)ei, flag);

    // ---- layer 1 ----
    hipMemsetAsync(bufA, 0, (size_t)N * IN_CH * sizeof(float), stream);
    {
        int total = E * (IN_CH / 4);
        scatter_add_kernel<IN_CH><<<(total + 255) / 256, 256, 0, stream>>>(
            x, ei, flag, bufA, E);
    }
    {
        int blocks = (N + 63) / 64;
        gemm_mlp_kernel<IN_CH, true><<<blocks, 256, 0, stream>>>(
            x, bufA, W1, b1, bufB, N);                         // t1
        gemm_mlp_kernel<HID, true><<<blocks, 256, 0, stream>>>(
            bufB, nullptr, W2, b2, bufC, N);                   // h1 = relu(conv1)
    }

    // ---- layer 2 ----
    hipMemsetAsync(bufA, 0, (size_t)N * HID * sizeof(float), stream);
    {
        int total = E * (HID / 4);
        scatter_add_kernel<HID><<<(total + 255) / 256, 256, 0, stream>>>(
            bufC, ei, flag, bufA, E);
    }
    {
        int blocks = (N + 63) / 64;
        gemm_mlp_kernel<HID, true><<<blocks, 256, 0, stream>>>(
            bufC, bufA, W3, b3, bufB, N);                      // t2
        gemm_mlp_kernel<HID, true><<<blocks, 256, 0, stream>>>(
            bufB, nullptr, W4, b4, bufC, N);                   // h2 = relu(conv2)
    }

    // ---- output head ----
    {
        int total = N * 64;
        out_dot_kernel<<<(total + 255) / 256, 256, 0, stream>>>(
            bufC, Wout, bout, out, N);
    }
}

// Round 2
// 700.756 us; speedup vs baseline: 3.5989x; 3.5989x over previous
//
#include <hip/hip_runtime.h>

// GIN: 2x GINConv(eps=0, MLP 2-layer) + ReLU, then Linear(128->1).
// N=50000 nodes, E=800000 edges, IN=64, HID=128.
//
// Round 2: replace float-atomic scatter (1.6GB HBM write-through, 2.0ms) with
// device-built CSR + wave-per-node gather aggregation (no float atomics).

#define N_NODES 50000
#define IN_CH 64
#define HID 128

// ---------------- edge dtype detection (int64 vs int32) ----------------
__global__ void detect64_kernel(const int* __restrict__ ei32, int* __restrict__ flag) {
    int t = threadIdx.x;  // 256 threads
    int v = ei32[2 * t + 1];
    unsigned long long b = __ballot(v != 0);
    __shared__ unsigned long long r[4];
    if ((t & 63) == 0) r[t >> 6] = b;
    __syncthreads();
    if (t == 0) flag[0] = ((r[0] | r[1] | r[2] | r[3]) == 0ULL) ? 1 : 0;
}

__device__ __forceinline__ int load_idx(const void* ei, int is64, int pos) {
    if (is64) return (int)((const long long*)ei)[pos];
    return ((const int*)ei)[pos];
}

// ---------------- CSR build ----------------
// K0: deg histogram (deg must be memset 0)
__global__ __launch_bounds__(256) void hist_kernel(
    const void* __restrict__ ei, const int* __restrict__ is64,
    int* __restrict__ deg, int E)
{
    int e = blockIdx.x * blockDim.x + threadIdx.x;
    if (e >= E) return;
    int d = load_idx(ei, *is64, E + e);
    atomicAdd(&deg[d], 1);
}

__device__ __forceinline__ int wave_incl_scan(int v, int lane) {
    #pragma unroll
    for (int off = 1; off < 64; off <<= 1) {
        int u = __shfl_up(v, off);
        if (lane >= off) v += u;
    }
    return v;
}

// K1: per-block (256-elem) inclusive scan of deg -> row_ptr[i] (temp), block sums
__global__ __launch_bounds__(256) void scan1_kernel(
    const int* __restrict__ deg, int* __restrict__ incl,
    int* __restrict__ bsum, int N)
{
    int i = blockIdx.x * 256 + threadIdx.x;
    int lane = threadIdx.x & 63;
    int w = threadIdx.x >> 6;
    int v = (i < N) ? deg[i] : 0;
    int s = wave_incl_scan(v, lane);
    __shared__ int wsum[4];
    if (lane == 63) wsum[w] = s;
    __syncthreads();
    int off = 0;
    #pragma unroll
    for (int k = 0; k < 4; k++) if (k < w) off += wsum[k];
    s += off;
    if (i < N) incl[i] = s;
    if (threadIdx.x == 255) bsum[blockIdx.x] = s;
}

// K2: single-block exclusive scan of block sums (nb <= 256)
__global__ __launch_bounds__(256) void scan2_kernel(
    const int* __restrict__ bsum, int* __restrict__ bsx, int nb)
{
    int t = threadIdx.x;
    int lane = t & 63;
    int w = t >> 6;
    int v = (t < nb) ? bsum[t] : 0;
    int s = wave_incl_scan(v, lane);
    __shared__ int wsum[4];
    if (lane == 63) wsum[w] = s;
    __syncthreads();
    int off = 0;
    #pragma unroll
    for (int k = 0; k < 4; k++) if (k < w) off += wsum[k];
    s += off;
    if (t < nb) bsx[t] = s - v;   // exclusive
}

// K3: finalize row_ptr (exclusive) in-place over incl; cursor := start offsets.
// row_ptr has N+1 entries. deg buffer is reused as cursor.
__global__ __launch_bounds__(256) void scan3_kernel(
    int* __restrict__ deg_cursor, int* __restrict__ incl_rowptr,
    const int* __restrict__ bsx, int N)
{
    int i = blockIdx.x * 256 + threadIdx.x;
    if (i >= N) return;
    int incl = incl_rowptr[i] + bsx[blockIdx.x];
    int d = deg_cursor[i];
    int excl = incl - d;
    incl_rowptr[i] = excl;        // row_ptr[i]
    deg_cursor[i] = excl;         // cursor[i]
    if (i == N - 1) incl_rowptr[N] = incl;
}

// K4: fill col[] via per-dst cursor atomics
__global__ __launch_bounds__(256) void fill_kernel(
    const void* __restrict__ ei, const int* __restrict__ is64,
    int* __restrict__ cursor, int* __restrict__ col, int E)
{
    int e = blockIdx.x * blockDim.x + threadIdx.x;
    if (e >= E) return;
    int i64 = *is64;
    int s = load_idx(ei, i64, e);
    int d = load_idx(ei, i64, E + e);
    int pos = atomicAdd(&cursor[d], 1);
    col[pos] = s;
}

// ---------------- gather aggregation: agg[n] = sum_{j in nbrs(n)} h[j] ----------------
// One wave per node. C=64: 1 float/lane; C=128: float2/lane (512B coalesced row).
template<int C>
__global__ __launch_bounds__(256) void gather_agg_kernel(
    const float* __restrict__ h, const int* __restrict__ rp,
    const int* __restrict__ col, float* __restrict__ agg, int N)
{
    int wid = (blockIdx.x * blockDim.x + threadIdx.x) >> 6;
    int lane = threadIdx.x & 63;
    if (wid >= N) return;
    int b = rp[wid], e2 = rp[wid + 1];
    float2 acc = make_float2(0.f, 0.f);
    for (int base = b; base < e2; base += 64) {
        int cnt = e2 - base; if (cnt > 64) cnt = 64;
        int myc = (base + lane < e2) ? col[base + lane] : 0;
        for (int j = 0; j < cnt; j++) {
            int s = __shfl(myc, j);
            if (C == 128) {
                float2 v = *(const float2*)(h + (size_t)s * C + lane * 2);
                acc.x += v.x; acc.y += v.y;
            } else {
                acc.x += h[(size_t)s * C + lane];
            }
        }
    }
    if (C == 128) {
        *(float2*)(agg + (size_t)wid * C + lane * 2) = acc;
    } else {
        agg[(size_t)wid * C + lane] = acc.x;
    }
}

// ---------------- fp32 GEMM: out[N][128] = act((A (+Aadd)) @ W + b) ----------------
template<int K, bool RELU>
__global__ __launch_bounds__(256) void gemm_mlp_kernel(
    const float* __restrict__ A, const float* __restrict__ Aadd,
    const float* __restrict__ W, const float* __restrict__ bias,
    float* __restrict__ out, int N)
{
    constexpr int KT = 64;
    constexpr int NT = 64;
    __shared__ float Ws[KT][128];
    __shared__ float As[NT][KT + 4];

    const int t  = threadIdx.x;
    const int tx = t & 31;
    const int ty = t >> 5;
    const int n0 = blockIdx.x * NT;

    float acc[8][4];
    #pragma unroll
    for (int i = 0; i < 8; i++)
        #pragma unroll
        for (int j = 0; j < 4; j++) acc[i][j] = 0.f;

    for (int k0 = 0; k0 < K; k0 += KT) {
        {
            int lr = t & 31;
            int kr = t >> 5;
            #pragma unroll
            for (int r = 0; r < KT; r += 8) {
                float4 v = *(const float4*)(W + (size_t)(k0 + kr + r) * 128 + lr * 4);
                *(float4*)&Ws[kr + r][lr * 4] = v;
            }
        }
        {
            constexpr int F4 = KT / 4;
            int g = t % F4;
            int r = t / F4;
            #pragma unroll
            for (int rr = 0; rr < NT; rr += 256 / F4) {
                int row = r + rr;
                int n = n0 + row;
                int nc = n < N ? n : N - 1;
                float4 v = *(const float4*)(A + (size_t)nc * K + k0 + g * 4);
                if (Aadd) {
                    float4 u = *(const float4*)(Aadd + (size_t)nc * K + k0 + g * 4);
                    v.x += u.x; v.y += u.y; v.z += u.z; v.w += u.w;
                }
                *(float4*)&As[row][g * 4] = v;
            }
        }
        __syncthreads();
        #pragma unroll
        for (int k = 0; k < KT; k += 4) {
            float4 w0 = *(const float4*)&Ws[k + 0][tx * 4];
            float4 w1 = *(const float4*)&Ws[k + 1][tx * 4];
            float4 w2 = *(const float4*)&Ws[k + 2][tx * 4];
            float4 w3 = *(const float4*)&Ws[k + 3][tx * 4];
            #pragma unroll
            for (int i = 0; i < 8; i++) {
                float4 a = *(const float4*)&As[ty * 8 + i][k];
                acc[i][0] += a.x * w0.x + a.y * w1.x + a.z * w2.x + a.w * w3.x;
                acc[i][1] += a.x * w0.y + a.y * w1.y + a.z * w2.y + a.w * w3.y;
                acc[i][2] += a.x * w0.z + a.y * w1.z + a.z * w2.z + a.w * w3.z;
                acc[i][3] += a.x * w0.w + a.y * w1.w + a.z * w2.w + a.w * w3.w;
            }
        }
        __syncthreads();
    }
    float4 b = *(const float4*)(bias + tx * 4);
    #pragma unroll
    for (int i = 0; i < 8; i++) {
        int n = n0 + ty * 8 + i;
        if (n < N) {
            float4 o;
            o.x = acc[i][0] + b.x; o.y = acc[i][1] + b.y;
            o.z = acc[i][2] + b.z; o.w = acc[i][3] + b.w;
            if (RELU) {
                o.x = fmaxf(o.x, 0.f); o.y = fmaxf(o.y, 0.f);
                o.z = fmaxf(o.z, 0.f); o.w = fmaxf(o.w, 0.f);
            }
            *(float4*)(out + (size_t)n * 128 + tx * 4) = o;
        }
    }
}

// ---------------- output head ----------------
__global__ __launch_bounds__(256) void out_dot_kernel(
    const float* __restrict__ h2, const float* __restrict__ Wout,
    const float* __restrict__ bout, float* __restrict__ out, int N)
{
    int gt = blockIdx.x * blockDim.x + threadIdx.x;
    int wave = gt >> 6;
    int lane = threadIdx.x & 63;
    if (wave >= N) return;
    const float* row = h2 + (size_t)wave * 128;
    float p = row[lane] * Wout[lane] + row[lane + 64] * Wout[lane + 64];
    #pragma unroll
    for (int off = 32; off; off >>= 1) p += __shfl_down(p, off);
    if (lane == 0) out[wave] = p + bout[0];
}

extern "C" void kernel_launch(void* const* d_in, const int* in_sizes, int n_in,
                              void* d_out, int out_size, void* d_ws, size_t ws_size,
                              hipStream_t stream) {
    const float* x    = (const float*)d_in[0];
    const void*  ei   = d_in[1];
    const float* W1   = (const float*)d_in[2];
    const float* b1   = (const float*)d_in[3];
    const float* W2   = (const float*)d_in[4];
    const float* b2   = (const float*)d_in[5];
    const float* W3   = (const float*)d_in[6];
    const float* b3   = (const float*)d_in[7];
    const float* W4   = (const float*)d_in[8];
    const float* b4   = (const float*)d_in[9];
    const float* Wout = (const float*)d_in[10];
    const float* bout = (const float*)d_in[11];
    float* out = (float*)d_out;

    const int E = in_sizes[1] / 2;
    const int N = N_NODES;
    const int nb = (N + 255) / 256;   // 196 scan blocks

    char* wsb = (char*)d_ws;
    int*   flag   = (int*)wsb;                         // 256 B
    int*   deg    = (int*)(wsb + 256);                 // N ints (reused as cursor)
    int*   rowptr = deg + N;                           // N+1 ints
    int*   bsum   = rowptr + N + 1;                    // 256 ints
    int*   bsx    = bsum + 256;                        // 256 ints
    int*   col    = bsx + 256;                         // E ints
    float* bufA   = (float*)(col + E);                 // N*128 (agg)
    float* bufB   = bufA + (size_t)N * HID;
    float* bufC   = bufB + (size_t)N * HID;

    detect64_kernel<<<1, 256, 0, stream>>>((const int*)ei, flag);

    // ---- build CSR (once, reused by both layers) ----
    hipMemsetAsync(deg, 0, (size_t)N * sizeof(int), stream);
    hist_kernel<<<(E + 255) / 256, 256, 0, stream>>>(ei, flag, deg, E);
    scan1_kernel<<<nb, 256, 0, stream>>>(deg, rowptr, bsum, N);
    scan2_kernel<<<1, 256, 0, stream>>>(bsum, bsx, nb);
    scan3_kernel<<<nb, 256, 0, stream>>>(deg, rowptr, bsx, N);  // deg becomes cursor
    fill_kernel<<<(E + 255) / 256, 256, 0, stream>>>(ei, flag, deg, col, E);

    const int agg_blocks = (N * 64 + 255) / 256;   // wave per node, 4 waves/block
    const int gemm_blocks = (N + 63) / 64;

    // ---- layer 1 ----
    gather_agg_kernel<IN_CH><<<agg_blocks, 256, 0, stream>>>(x, rowptr, col, bufA, N);
    gemm_mlp_kernel<IN_CH, true><<<gemm_blocks, 256, 0, stream>>>(
        x, bufA, W1, b1, bufB, N);                     // t1
    gemm_mlp_kernel<HID, true><<<gemm_blocks, 256, 0, stream>>>(
        bufB, nullptr, W2, b2, bufC, N);               // h1

    // ---- layer 2 ----
    gather_agg_kernel<HID><<<agg_blocks, 256, 0, stream>>>(bufC, rowptr, col, bufA, N);
    gemm_mlp_kernel<HID, true><<<gemm_blocks, 256, 0, stream>>>(
        bufC, bufA, W3, b3, bufB, N);                  // t2
    gemm_mlp_kernel<HID, true><<<gemm_blocks, 256, 0, stream>>>(
        bufB, nullptr, W4, b4, bufC, N);               // h2

    // ---- output head ----
    out_dot_kernel<<<(N * 64 + 255) / 256, 256, 0, stream>>>(
        bufC, Wout, bout, out, N);
}